// Round 11
// baseline (234.237 us; speedup 1.0000x reference)
//
#include <hip/hip_runtime.h>
#include <hip/hip_bf16.h>

#define NU 262144
#define NU2 131072      // units per pass (2 passes share one 64MB h buffer)
#define GG 128
#define PG 134          // padded field side (128 + 2*3)
#define DD 128
#define NCELL 4096      // 16^3 cells of 8^3 voxels

typedef __attribute__((ext_vector_type(8))) short short8;   // 8 bf16 MFMA frag
typedef __attribute__((ext_vector_type(4))) float f32x4;
typedef __attribute__((ext_vector_type(2))) unsigned uint2v;

union Frag { short8 s; unsigned u[4]; };

// fp32 -> bf16 RNE (prep kernels)
__device__ __forceinline__ unsigned short f2b(float f) {
  union { float f; unsigned u; } v; v.f = f;
  unsigned r = v.u + 0x7fffu + ((v.u >> 16) & 1u);
  return (unsigned short)(r >> 16);
}
// packed fp32x2 -> bf16x2 (RNE HW instr)
__device__ __forceinline__ unsigned cvtpk(float lo, float hi) {
  unsigned r;
  asm("v_cvt_pk_bf16_f32 %0, %1, %2" : "=v"(r) : "v"(lo), "v"(hi));
  return r;
}

__device__ __forceinline__ float fast_tanh(float x) {
  float ax = fabsf(x);
  float e  = __expf(ax + ax);
  float t  = 1.0f - __fdividef(2.0f, e + 1.0f);
  return copysignf(t, x);
}

// 128 neighborhood offsets = 18 z-rows of 7 + one 2-elem stub (+1 dead row)
struct alignas(16) RowdT { int v[20]; };
static constexpr RowdT mkrowd() {
  RowdT t{};
  for (int r = 0; r < 20; ++r) {
    int rr = (r < 18) ? r : 18;
    int di = (rr < 18) ? (-3 + rr / 7) : -1;
    int dj = (rr < 18) ? (-3 + rr % 7) : 1;
    t.v[r] = (di * PG + dj) * PG - 3;
  }
  return t;
}
__device__ constexpr RowdT ROWD = mkrowd();

__device__ __forceinline__ int cell_of(float px, float py, float pz) {
  int cx = min(max((int)px, 0), GG - 1) >> 3;
  int cy = min(max((int)py, 0), GG - 1) >> 3;
  int cz = min(max((int)pz, 0), GG - 1) >> 3;
  return (cx << 8) | (cy << 4) | cz;
}

// ---------------- prep 1: clamped pad + bf16 field ----------------
__global__ void prep_field(const float* __restrict__ f, unsigned short* __restrict__ fp) {
  int idx = blockIdx.x * 256 + threadIdx.x;
  if (idx >= PG * PG * PG) return;
  int z = idx % PG, t = idx / PG;
  int y = t % PG, x = t / PG;
  int xx = min(max(x - 3, 0), GG - 1);
  int yy = min(max(y - 3, 0), GG - 1);
  int zz = min(max(z - 3, 0), GG - 1);
  fp[idx] = f2b(f[(xx * GG + yy) * GG + zz]);
}

// ---------------- prep 2: weight wall (13 x 8KB) + cursor zero ----------------
// kt 0-3: W1 sig half; kt 4-8: W1 gather rows (reordered, zero-padded); kt 9-12: W2.
__global__ void prep_w(const float* __restrict__ W1, const float* __restrict__ W2,
                       unsigned short* __restrict__ wall, int* __restrict__ cursor) {
  int idx = blockIdx.x * 256 + threadIdx.x;
  if (cursor && idx < NCELL) cursor[idx] = 0;
  if (idx >= 6656) return;
  int kt = idx >> 9, nt = (idx >> 6) & 7, ln = idx & 63;
  int n = nt * 16 + (ln & 15), lg = ln >> 4;
  short8 s;
  if (kt < 4) {
    int k0 = kt * 32 + lg * 8;
#pragma unroll
    for (int j = 0; j < 8; ++j) s[j] = (short)f2b(W1[(k0 + j) * DD + n]);
  } else if (kt < 9) {
    int r = (kt - 4) * 4 + lg;                 // 0..19
#pragma unroll
    for (int j = 0; j < 8; ++j) {
      bool valid = (r < 18 && j < 7) || (r == 18 && j < 2);
      int row = 128 + ((r < 18) ? (r * 7 + j) : (126 + j));
      s[j] = valid ? (short)f2b(W1[row * DD + n]) : (short)0;
    }
  } else {
    int k0 = (kt - 9) * 32 + lg * 8;
#pragma unroll
    for (int j = 0; j < 8; ++j) s[j] = (short)f2b(W2[(k0 + j) * DD + n]);
  }
  ((short8*)wall)[idx] = s;
}

// ---------------- counting sort by cell ----------------
__global__ void hist_k(const float* __restrict__ pos, int* __restrict__ cursor) {
  int u = blockIdx.x * 256 + threadIdx.x;
  atomicAdd(&cursor[cell_of(pos[u * 3], pos[u * 3 + 1], pos[u * 3 + 2])], 1);
}
__global__ void scan_k(int* __restrict__ cursor) {
  __shared__ int sums[256];
  int t = threadIdx.x;
  int local[16];
  int partial = 0;
#pragma unroll
  for (int j = 0; j < 16; ++j) { local[j] = cursor[t * 16 + j]; partial += local[j]; }
  sums[t] = partial;
  __syncthreads();
  for (int off = 1; off < 256; off <<= 1) {
    int v = (t >= off) ? sums[t - off] : 0;
    __syncthreads();
    sums[t] += v;
    __syncthreads();
  }
  int excl = sums[t] - partial;
#pragma unroll
  for (int j = 0; j < 16; ++j) { cursor[t * 16 + j] = excl; excl += local[j]; }
}
__global__ void scatter_k(const float* __restrict__ pos, const float* __restrict__ offs,
                          int* __restrict__ cursor, int* __restrict__ perm,
                          float* __restrict__ posP, float* __restrict__ offsP) {
  int u = blockIdx.x * 256 + threadIdx.x;
  float px = pos[u * 3 + 0], py = pos[u * 3 + 1], pz = pos[u * 3 + 2];
  int dst = atomicAdd(&cursor[cell_of(px, py, pz)], 1);
  perm[dst] = u;
  posP[dst * 3 + 0] = px; posP[dst * 3 + 1] = py; posP[dst * 3 + 2] = pz;
  offsP[dst * 3 + 0] = offs[u * 3 + 0];
  offsP[dst * 3 + 1] = offs[u * 3 + 1];
  offsP[dst * 3 + 2] = offs[u * 3 + 2];
}

// ================ k1: gather + GEMM1 + tanh -> h (row-major bf16) ================
// 8 waves/block, wave = 16 units x {ev0,ev1}. W1 (9x8KB) one-shot in LDS.
template<bool SORT>
__global__ __launch_bounds__(512, 2) __attribute__((amdgpu_waves_per_eu(2, 4)))
void atu_g1(const float* __restrict__ pos, const float* __restrict__ sig,
            const float* __restrict__ offs, const int* __restrict__ perm,
            const float* __restrict__ b1,
            const unsigned short* __restrict__ fpad, const unsigned short* __restrict__ wall,
            unsigned short* __restrict__ hbuf, int pass)
{
  __shared__ unsigned short ldsw[9][4096];     // 72 KB: all 9 GEMM1 kt-blocks
  const int tid = threadIdx.x, lane = tid & 63;
  const int lg = lane >> 4, lm = lane & 15, wid = tid >> 6;
  int bid = blockIdx.x;
  int swz = (bid & 7) * 128 + (bid >> 3);      // 1024 blocks/pass, XCD-bijective
  const int ub = pass * NU2 + swz * 128 + wid * 16;

  // one-shot weight staging
  const short8* wfr = (const short8*)wall;
#pragma unroll
  for (int i = 0; i < 9; ++i)
    ((short8*)ldsw)[i * 512 + tid] = wfr[i * 512 + tid];

  const int pv = SORT ? perm[ub + lm] : (ub + lm);

  // gather bases (ev0/ev1)
  int abase[2];
  {
    int u = ub + lm;
    float px = pos[u * 3 + 0], py = pos[u * 3 + 1], pz = pos[u * 3 + 2];
    float qx = px + offs[u * 3 + 0], qy = py + offs[u * 3 + 1], qz = pz + offs[u * 3 + 2];
    int ax = min(max((int)px, 0), GG - 1), ay = min(max((int)py, 0), GG - 1), az = min(max((int)pz, 0), GG - 1);
    int bx = min(max((int)qx, 0), GG - 1), by = min(max((int)qy, 0), GG - 1), bz = min(max((int)qz, 0), GG - 1);
    abase[0] = ((ax + 3) * PG + (ay + 3)) * PG + (az + 3);
    abase[1] = ((bx + 3) * PG + (by + 3)) * PG + (bz + 3);
  }
  __syncthreads();

  f32x4 acc0[8], acc1[8];
#pragma unroll
  for (int nt = 0; nt < 8; ++nt) acc0[nt] = f32x4{0.f, 0.f, 0.f, 0.f};

  const float* sp = sig + (size_t)pv * DD + lg * 8;
  // ---- sig kts 0-3 (ev-shared), depth-1 prefetch ----
  {
    f32x4 pa = *(const f32x4*)(sp), pb = *(const f32x4*)(sp + 4);
#pragma unroll 1
    for (int kt = 0; kt < 4; ++kt) {
      f32x4 na, nb;
      if (kt < 3) { na = *(const f32x4*)(sp + (kt + 1) * 32); nb = *(const f32x4*)(sp + (kt + 1) * 32 + 4); }
      Frag B;
      B.u[0] = cvtpk(pa[0], pa[1]); B.u[1] = cvtpk(pa[2], pa[3]);
      B.u[2] = cvtpk(pb[0], pb[1]); B.u[3] = cvtpk(pb[2], pb[3]);
      const char* buf = (const char*)ldsw + kt * 8192;
#pragma unroll
      for (int nt = 0; nt < 8; ++nt) {
        short8 af = *(const short8*)(buf + (nt * 64 + lane) * 16);
        acc0[nt] = __builtin_amdgcn_mfma_f32_16x16x32_bf16(af, B.s, acc0[nt], 0, 0, 0);
      }
      pa = na; pb = nb;
    }
  }
#pragma unroll
  for (int nt = 0; nt < 8; ++nt) acc1[nt] = acc0[nt];

  // ---- row kts 4-8 (per-ev gathers), depth-1 prefetch ----
  {
    const char* fpadb = (const char*)fpad;
    int rd = ROWD.v[lg];
    short8 rA = *(const short8*)(fpadb + 2 * (size_t)(abase[0] + rd));
    short8 rB = *(const short8*)(fpadb + 2 * (size_t)(abase[1] + rd));
#pragma unroll 1
    for (int kt = 4; kt < 9; ++kt) {
      short8 nA, nB;
      if (kt < 8) {
        int rn = ROWD.v[(kt - 3) * 4 + lg];
        nA = *(const short8*)(fpadb + 2 * (size_t)(abase[0] + rn));
        nB = *(const short8*)(fpadb + 2 * (size_t)(abase[1] + rn));
      }
      const char* buf = (const char*)ldsw + kt * 8192;
#pragma unroll
      for (int nt = 0; nt < 8; ++nt) {
        short8 af = *(const short8*)(buf + (nt * 64 + lane) * 16);
        acc0[nt] = __builtin_amdgcn_mfma_f32_16x16x32_bf16(af, rA, acc0[nt], 0, 0, 0);
        acc1[nt] = __builtin_amdgcn_mfma_f32_16x16x32_bf16(af, rB, acc1[nt], 0, 0, 0);
      }
      rA = nA; rB = nB;
    }
  }

  // ---- bias + tanh -> h rows (plain [col][128] bf16) ----
  int hc = ub + lm - pass * NU2;
  unsigned short* h0 = hbuf + (size_t)hc * DD;
  unsigned short* h1 = hbuf + (size_t)(NU2 + hc) * DD;
#pragma unroll
  for (int nt = 0; nt < 8; ++nt) {
    f32x4 b1v = *(const f32x4*)(b1 + nt * 16 + lg * 4);
    float a0 = fast_tanh(acc0[nt][0] + b1v[0]);
    float a1 = fast_tanh(acc0[nt][1] + b1v[1]);
    float a2 = fast_tanh(acc0[nt][2] + b1v[2]);
    float a3 = fast_tanh(acc0[nt][3] + b1v[3]);
    uint2v w0; w0[0] = cvtpk(a0, a1); w0[1] = cvtpk(a2, a3);
    *(uint2v*)(h0 + nt * 16 + lg * 4) = w0;
    float c0 = fast_tanh(acc1[nt][0] + b1v[0]);
    float c1 = fast_tanh(acc1[nt][1] + b1v[1]);
    float c2 = fast_tanh(acc1[nt][2] + b1v[2]);
    float c3 = fast_tanh(acc1[nt][3] + b1v[3]);
    uint2v w1; w1[0] = cvtpk(c0, c1); w1[1] = cvtpk(c2, c3);
    *(uint2v*)(h1 + nt * 16 + lg * 4) = w1;
  }
}

// ================ k2: GEMM2 + norm + accept/outputs ================
// 4 waves/block, wave = 16 units x {ev0,ev1}. W2 (4x8KB) one-shot in LDS.
template<bool SORT>
__global__ __launch_bounds__(256, 2) __attribute__((amdgpu_waves_per_eu(2, 4)))
void atu_g2(const float* __restrict__ posP, const float* __restrict__ sig,
            const float* __restrict__ offsP, const int* __restrict__ perm,
            const float* __restrict__ b2, const unsigned short* __restrict__ wall,
            const unsigned short* __restrict__ hbuf,
            float* __restrict__ out_stab, float* __restrict__ out_pos, int pass)
{
  __shared__ unsigned short ldsw[4][4096];     // 32 KB: W2
  const int tid = threadIdx.x, lane = tid & 63;
  const int lg = lane >> 4, lm = lane & 15, wid = tid >> 6;
  int bid = blockIdx.x;
  int swz = (bid & 7) * 256 + (bid >> 3);      // 2048 blocks/pass, XCD-bijective
  const int ub = pass * NU2 + swz * 64 + wid * 16;

  const short8* wfr = (const short8*)wall + 9 * 512;   // kt 9..12
#pragma unroll
  for (int i = 0; i < 8; ++i)
    ((short8*)ldsw)[i * 256 + tid] = wfr[i * 256 + tid];

  const int pv = SORT ? perm[ub + lm] : (ub + lm);
  int hc = ub + lm - pass * NU2;
  const unsigned short* h0 = hbuf + (size_t)hc * DD;
  const unsigned short* h1 = hbuf + (size_t)(NU2 + hc) * DD;
  __syncthreads();

  f32x4 acc0[8], acc1[8];
#pragma unroll
  for (int nt = 0; nt < 8; ++nt) {
    f32x4 b2v = *(const f32x4*)(b2 + nt * 16 + lg * 4);
    acc0[nt] = b2v; acc1[nt] = b2v;
  }

#pragma unroll 1
  for (int kt = 0; kt < 4; ++kt) {
    short8 B0 = *(const short8*)(h0 + kt * 32 + lg * 8);
    short8 B1 = *(const short8*)(h1 + kt * 32 + lg * 8);
    const char* buf = (const char*)ldsw + kt * 8192;
#pragma unroll
    for (int nt = 0; nt < 8; ++nt) {
      short8 af = *(const short8*)(buf + (nt * 64 + lane) * 16);
      acc0[nt] = __builtin_amdgcn_mfma_f32_16x16x32_bf16(af, B0, acc0[nt], 0, 0, 0);
      acc1[nt] = __builtin_amdgcn_mfma_f32_16x16x32_bf16(af, B1, acc1[nt], 0, 0, 0);
    }
  }

  // || resp - sig ||^2 (sig f32 direct)
  float ssq0 = 0.f, ssq1 = 0.f;
#pragma unroll
  for (int nt = 0; nt < 8; ++nt) {
    f32x4 sv = *(const f32x4*)(sig + (size_t)pv * DD + nt * 16 + lg * 4);
#pragma unroll
    for (int r = 0; r < 4; ++r) {
      float d0 = acc0[nt][r] - sv[r];
      float d1 = acc1[nt][r] - sv[r];
      ssq0 = fmaf(d0, d0, ssq0);
      ssq1 = fmaf(d1, d1, ssq1);
    }
  }
  ssq0 += __shfl_xor(ssq0, 16, 64); ssq0 += __shfl_xor(ssq0, 32, 64);
  ssq1 += __shfl_xor(ssq1, 16, 64); ssq1 += __shfl_xor(ssq1, 32, 64);

  if (lane < 16) {
    int ul = ub + lm;
    float px = posP[ul * 3 + 0], py = posP[ul * 3 + 1], pz = posP[ul * 3 + 2];
    float ox = offsP[ul * 3 + 0], oy = offsP[ul * 3 + 1], oz = offsP[ul * 3 + 2];
    bool ok = ssq1 <= ssq0;
    out_stab[pv] = sqrtf(ok ? ssq1 : ssq0);
    out_pos[pv * 3 + 0] = ok ? px + ox : px;
    out_pos[pv * 3 + 1] = ok ? py + oy : py;
    out_pos[pv * 3 + 2] = ok ? pz + oz : pz;
  }
}

extern "C" void kernel_launch(void* const* d_in, const int* in_sizes, int n_in,
                              void* d_out, int out_size, void* d_ws, size_t ws_size,
                              hipStream_t stream) {
  const float* field = (const float*)d_in[0];
  const float* pos   = (const float*)d_in[1];
  const float* sig   = (const float*)d_in[2];
  const float* offs  = (const float*)d_in[3];
  const float* W1    = (const float*)d_in[4];
  const float* b1    = (const float*)d_in[5];
  const float* W2    = (const float*)d_in[6];
  const float* b2    = (const float*)d_in[7];
  float* out_stab = (float*)d_out;
  float* out_pos  = out_stab + NU;

  char* ws = (char*)d_ws;
  unsigned short* fpad  = (unsigned short*)ws;                 // 4,812,208 B (+slack)
  unsigned short* wall  = (unsigned short*)(ws + 4812800);     // 106,496 B (13 x 8KB)
  float*          posP  = (float*)(ws + 4919296);              // 3,145,728 B
  float*          offsP = (float*)(ws + 8065024);              // 3,145,728 B
  int*            perm  = (int*)(ws + 11210752);               // 1,048,576 B
  int*            cursor= (int*)(ws + 12259328);               // 16,384 B
  unsigned short* hbuf  = (unsigned short*)(ws + 12275712);    // 67,108,864 B (2*NU2*128 bf16)
  const size_t need_sort  = 12275712ull + 67108864ull;         // 79,384,576
  const size_t need_plain = 4919296ull + 67108864ull;          // (hbuf moved down in plain mode)

  prep_field<<<(PG * PG * PG + 255) / 256, 256, 0, stream>>>(field, fpad);

  if (ws_size >= need_sort) {
    prep_w<<<26, 256, 0, stream>>>(W1, W2, wall, cursor);
    hist_k<<<NU / 256, 256, 0, stream>>>(pos, cursor);
    scan_k<<<1, 256, 0, stream>>>(cursor);
    scatter_k<<<NU / 256, 256, 0, stream>>>(pos, offs, cursor, perm, posP, offsP);
    for (int pass = 0; pass < 2; ++pass) {
      atu_g1<true><<<NU2 / 128, 512, 0, stream>>>(posP, sig, offsP, perm, b1,
                                                  fpad, wall, hbuf, pass);
      atu_g2<true><<<NU2 / 64, 256, 0, stream>>>(posP, sig, offsP, perm, b2, wall,
                                                 hbuf, out_stab, out_pos, pass);
    }
  } else if (ws_size >= need_plain) {
    unsigned short* hb2 = (unsigned short*)(ws + 4919296);
    prep_w<<<26, 256, 0, stream>>>(W1, W2, wall, nullptr);
    for (int pass = 0; pass < 2; ++pass) {
      atu_g1<false><<<NU2 / 128, 512, 0, stream>>>(pos, sig, offs, nullptr, b1,
                                                   fpad, wall, hb2, pass);
      atu_g2<false><<<NU2 / 64, 256, 0, stream>>>(pos, sig, offs, nullptr, b2, wall,
                                                  hb2, out_stab, out_pos, pass);
    }
  }
}

// Round 12
// 149.631 us; speedup vs baseline: 1.5654x; 1.5654x over previous
//
#include <hip/hip_runtime.h>
#include <hip/hip_bf16.h>

#define NU 262144
#define GG 128
#define PG 134          // padded field side (128 + 2*3)
#define DD 128

typedef __attribute__((ext_vector_type(8))) short short8;   // 8 bf16 MFMA frag
typedef __attribute__((ext_vector_type(4))) float f32x4;

union Frag { short8 s; unsigned u[4]; };

// fp32 -> bf16 RNE (prep kernels)
__device__ __forceinline__ unsigned short f2b(float f) {
  union { float f; unsigned u; } v; v.f = f;
  unsigned r = v.u + 0x7fffu + ((v.u >> 16) & 1u);
  return (unsigned short)(r >> 16);
}
// packed fp32x2 -> bf16x2 (RNE HW instr)
__device__ __forceinline__ unsigned cvtpk(float lo, float hi) {
  unsigned r;
  asm("v_cvt_pk_bf16_f32 %0, %1, %2" : "=v"(r) : "v"(lo), "v"(hi));
  return r;
}

__device__ __forceinline__ float fast_tanh(float x) {
  float ax = fabsf(x);
  float e  = __expf(ax + ax);
  float t  = 1.0f - __fdividef(2.0f, e + 1.0f);
  return copysignf(t, x);
}

// 128 neighborhood offsets = 18 z-rows of 7 + one 2-elem stub (+1 dead row)
struct alignas(16) RowdT { int v[20]; };
static constexpr RowdT mkrowd() {
  RowdT t{};
  for (int r = 0; r < 20; ++r) {
    int rr = (r < 18) ? r : 18;
    int di = (rr < 18) ? (-3 + rr / 7) : -1;
    int dj = (rr < 18) ? (-3 + rr % 7) : 1;
    t.v[r] = (di * PG + dj) * PG - 3;
  }
  return t;
}
__device__ constexpr RowdT ROWD = mkrowd();

// ---------------- prep 1: clamped pad + bf16 field ----------------
__global__ void prep_field(const float* __restrict__ f, unsigned short* __restrict__ fp) {
  int idx = blockIdx.x * 256 + threadIdx.x;
  if (idx >= PG * PG * PG) return;
  int z = idx % PG, t = idx / PG;
  int y = t % PG, x = t / PG;
  int xx = min(max(x - 3, 0), GG - 1);
  int yy = min(max(y - 3, 0), GG - 1);
  int zz = min(max(z - 3, 0), GG - 1);
  fp[idx] = f2b(f[(xx * GG + yy) * GG + zz]);
}

// ---------------- prep 2: weight wall (13 x 8KB) ----------------
// kt 0-3: W1 sig half; kt 4-8: W1 gather rows (reordered, zero-padded); kt 9-12: W2.
__global__ void prep_w(const float* __restrict__ W1, const float* __restrict__ W2,
                       unsigned short* __restrict__ wall) {
  int idx = blockIdx.x * 256 + threadIdx.x;
  if (idx >= 6656) return;
  int kt = idx >> 9, nt = (idx >> 6) & 7, ln = idx & 63;
  int n = nt * 16 + (ln & 15), lg = ln >> 4;
  short8 s;
  if (kt < 4) {
    int k0 = kt * 32 + lg * 8;
#pragma unroll
    for (int j = 0; j < 8; ++j) s[j] = (short)f2b(W1[(k0 + j) * DD + n]);
  } else if (kt < 9) {
    int r = (kt - 4) * 4 + lg;                 // 0..19
#pragma unroll
    for (int j = 0; j < 8; ++j) {
      bool valid = (r < 18 && j < 7) || (r == 18 && j < 2);
      int row = 128 + ((r < 18) ? (r * 7 + j) : (126 + j));
      s[j] = valid ? (short)f2b(W1[row * DD + n]) : (short)0;
    }
  } else {
    int k0 = (kt - 9) * 32 + lg * 8;
#pragma unroll
    for (int j = 0; j < 8; ++j) s[j] = (short)f2b(W2[(k0 + j) * DD + n]);
  }
  ((short8*)wall)[idx] = s;
}

// ---------------- main: 8 waves/block, wave = 16 units x {ev0, ev1} ----------------
// NATURAL unit order (no sort): sig/pos/offs/outputs fully coalesced; field rows
// are random but L2-resident. Weights: 2-kt phases through 2x16KB LDS buffers,
// register prefetch depth 2, 7 barriers. setprio(1) around MFMA clusters.
__global__ __launch_bounds__(512, 4) void atu_main(
    const float* __restrict__ pos, const float* __restrict__ sig,
    const float* __restrict__ offs,
    const float* __restrict__ b1, const float* __restrict__ b2,
    const unsigned short* __restrict__ fpad, const unsigned short* __restrict__ wall,
    float* __restrict__ out_stab, float* __restrict__ out_pos)
{
  __shared__ unsigned short ldsw[2][8192];   // 2 x 16KB weight buffers (pair of kt-blocks)
  const int tid  = threadIdx.x;
  const int lane = tid & 63;
  const int lg   = lane >> 4, lm = lane & 15;
  const int wid  = tid >> 6;
  int bid = blockIdx.x;
  int swz = (bid & 7) * 256 + (bid >> 3);      // XCD-bijective (2048 % 8 == 0)
  const int ub = swz * 128 + wid * 16;         // 16 units per wave
  const int un = ub + lm;                      // this lane-group's unit (natural order)

  // gather bases: ev0 / ev1
  int abase[2];
  {
    float px = pos[un * 3 + 0], py = pos[un * 3 + 1], pz = pos[un * 3 + 2];
    float qx = px + offs[un * 3 + 0], qy = py + offs[un * 3 + 1], qz = pz + offs[un * 3 + 2];
    int ax = min(max((int)px, 0), GG - 1), ay = min(max((int)py, 0), GG - 1), az = min(max((int)pz, 0), GG - 1);
    int bx = min(max((int)qx, 0), GG - 1), by = min(max((int)qy, 0), GG - 1), bz = min(max((int)qz, 0), GG - 1);
    abase[0] = ((ax + 3) * PG + (ay + 3)) * PG + (az + 3);
    abase[1] = ((bx + 3) * PG + (by + 3)) * PG + (bz + 3);
  }

  const short8* wfr = (const short8*)wall;     // frag idx = kt*512 + tid
  const char* fpadb = (const char*)fpad;

  f32x4 acc[8][2];
#pragma unroll
  for (int nt = 0; nt < 8; ++nt) { acc[nt][0] = f32x4{0.f,0.f,0.f,0.f}; acc[nt][1] = f32x4{0.f,0.f,0.f,0.f}; }
  f32x4 acc2[8][2];
  unsigned Q[2][8][2];

#define WRBUF(H, R0, R1)                                                        \
  *(short8*)((char*)&ldsw[H][0] + tid * 16) = (R0);                             \
  *(short8*)((char*)&ldsw[H][0] + 8192 + tid * 16) = (R1);

#define SIG_KT(KT, HALF)                                                        \
  {                                                                             \
    const f32x4* sp = (const f32x4*)(sig + (size_t)un * DD + (KT) * 32 + lg * 8); \
    f32x4 a = sp[0], b = sp[1];                                                 \
    Frag B;                                                                     \
    B.u[0] = cvtpk(a[0], a[1]); B.u[1] = cvtpk(a[2], a[3]);                     \
    B.u[2] = cvtpk(b[0], b[1]); B.u[3] = cvtpk(b[2], b[3]);                     \
    const char* buf = (const char*)&ldsw[HALF][0] + (((KT) & 1) ? 8192 : 0);    \
    __builtin_amdgcn_s_setprio(1);                                              \
    _Pragma("unroll")                                                           \
    for (int nt = 0; nt < 8; ++nt) {                                            \
      short8 af = *(const short8*)(buf + (nt * 64 + lane) * 16);                \
      acc[nt][0] = __builtin_amdgcn_mfma_f32_16x16x32_bf16(af, B.s, acc[nt][0], 0, 0, 0); \
    }                                                                           \
    __builtin_amdgcn_s_setprio(0);                                              \
  }

#define ROW_KT(KT, HALF)                                                        \
  {                                                                             \
    int rd = ROWD.v[((KT) - 4) * 4 + lg];                                       \
    short8 B0 = *(const short8*)(fpadb + 2 * (size_t)(abase[0] + rd));          \
    short8 B1 = *(const short8*)(fpadb + 2 * (size_t)(abase[1] + rd));          \
    const char* buf = (const char*)&ldsw[HALF][0] + (((KT) & 1) ? 8192 : 0);    \
    __builtin_amdgcn_s_setprio(1);                                              \
    _Pragma("unroll")                                                           \
    for (int nt = 0; nt < 8; ++nt) {                                            \
      short8 af = *(const short8*)(buf + (nt * 64 + lane) * 16);                \
      acc[nt][0] = __builtin_amdgcn_mfma_f32_16x16x32_bf16(af, B0, acc[nt][0], 0, 0, 0); \
      acc[nt][1] = __builtin_amdgcn_mfma_f32_16x16x32_bf16(af, B1, acc[nt][1], 0, 0, 0); \
    }                                                                           \
    __builtin_amdgcn_s_setprio(0);                                              \
  }

#define G2_KT(KT, HALF)                                                         \
  {                                                                             \
    constexpr int kb = (KT) - 9;                                                \
    Frag W[2];                                                                  \
    _Pragma("unroll")                                                           \
    for (int ut = 0; ut < 2; ++ut) {                                            \
      int qa0 = (int)Q[ut][2 * kb][0],     qa1 = (int)Q[ut][2 * kb][1];         \
      int qb0 = (int)Q[ut][2 * kb + 1][0], qb1 = (int)Q[ut][2 * kb + 1][1];     \
      int r00 = __builtin_amdgcn_ds_bpermute(ad0, qa0);                         \
      int r01 = __builtin_amdgcn_ds_bpermute(ad0, qa1);                         \
      int r10 = __builtin_amdgcn_ds_bpermute(ad1, qa0);                         \
      int r11 = __builtin_amdgcn_ds_bpermute(ad1, qa1);                         \
      int s00 = __builtin_amdgcn_ds_bpermute(ad0, qb0);                         \
      int s01 = __builtin_amdgcn_ds_bpermute(ad0, qb1);                         \
      int s10 = __builtin_amdgcn_ds_bpermute(ad1, qb0);                         \
      int s11 = __builtin_amdgcn_ds_bpermute(ad1, qb1);                         \
      W[ut].u[0] = (unsigned)(hi ? s00 : r00);                                  \
      W[ut].u[1] = (unsigned)(hi ? s01 : r01);                                  \
      W[ut].u[2] = (unsigned)(hi ? s10 : r10);                                  \
      W[ut].u[3] = (unsigned)(hi ? s11 : r11);                                  \
    }                                                                           \
    const char* buf = (const char*)&ldsw[HALF][0] + (((KT) & 1) ? 8192 : 0);    \
    __builtin_amdgcn_s_setprio(1);                                              \
    _Pragma("unroll")                                                           \
    for (int nt = 0; nt < 8; ++nt) {                                            \
      short8 af = *(const short8*)(buf + (nt * 64 + lane) * 16);                \
      acc2[nt][0] = __builtin_amdgcn_mfma_f32_16x16x32_bf16(af, W[0].s, acc2[nt][0], 0, 0, 0); \
      acc2[nt][1] = __builtin_amdgcn_mfma_f32_16x16x32_bf16(af, W[1].s, acc2[nt][1], 0, 0, 0); \
    }                                                                           \
    __builtin_amdgcn_s_setprio(0);                                              \
  }

  const int ad0 = ((((2 * lg) & 3) * 16) + lm) * 4;       // bpermute byte addrs
  const int ad1 = ((((2 * lg + 1) & 3) * 16) + lm) * 4;
  const bool hi = (lg >= 2);

  // ---- prologue: load pairs 0,1; stage pair0 ----
  short8 c0 = wfr[tid],        c1 = wfr[512 + tid];
  short8 n0 = wfr[1024 + tid], n1 = wfr[1536 + tid];
  WRBUF(0, c0, c1)
  __syncthreads();

  // P0: kts 0,1 (sig) from buf0; issue pair2; write pair1
  c0 = wfr[2048 + tid]; c1 = wfr[2560 + tid];
  SIG_KT(0, 0) SIG_KT(1, 0)
  WRBUF(1, n0, n1)
  __syncthreads();

  // P1: kts 2,3 (sig) from buf1; issue pair3; write pair2
  n0 = wfr[3072 + tid]; n1 = wfr[3584 + tid];
  SIG_KT(2, 1) SIG_KT(3, 1)
  WRBUF(0, c0, c1)
  __syncthreads();

  // sig contribution is shared by both evs
#pragma unroll
  for (int nt = 0; nt < 8; ++nt) acc[nt][1] = acc[nt][0];

  // P2: kts 4,5 (rows) from buf0; issue pair4; write pair3
  c0 = wfr[4096 + tid]; c1 = wfr[4608 + tid];
  ROW_KT(4, 0) ROW_KT(5, 0)
  WRBUF(1, n0, n1)
  __syncthreads();

  // P3: kts 6,7 (rows) from buf1; issue pair5; write pair4
  n0 = wfr[5120 + tid]; n1 = wfr[5632 + tid];
  ROW_KT(6, 1) ROW_KT(7, 1)
  WRBUF(0, c0, c1)
  __syncthreads();

  // P4: kt8 (row) + tanh/pack + kt9 (GEMM2) from buf0; issue block12; write pair5
  c0 = wfr[6144 + tid];
  ROW_KT(8, 0)

  // bias + tanh + pack h (lane-local bf16x2 words)
#pragma unroll
  for (int nt = 0; nt < 8; ++nt) {
    f32x4 b1v = *(const f32x4*)(b1 + nt * 16 + lg * 4);
#pragma unroll
    for (int ut = 0; ut < 2; ++ut) {
      float h0 = fast_tanh(acc[nt][ut][0] + b1v[0]);
      float h1 = fast_tanh(acc[nt][ut][1] + b1v[1]);
      float h2 = fast_tanh(acc[nt][ut][2] + b1v[2]);
      float h3 = fast_tanh(acc[nt][ut][3] + b1v[3]);
      Q[ut][nt][0] = cvtpk(h0, h1);
      Q[ut][nt][1] = cvtpk(h2, h3);
    }
  }
  // init acc2 with b2 (C-init)
#pragma unroll
  for (int nt = 0; nt < 8; ++nt) {
    f32x4 b2v = *(const f32x4*)(b2 + nt * 16 + lg * 4);
    acc2[nt][0] = b2v; acc2[nt][1] = b2v;
  }

  G2_KT(9, 0)
  WRBUF(1, n0, n1)
  __syncthreads();

  // P5: kts 10,11 (GEMM2) from buf1; write block12 to buf0 sub0
  G2_KT(10, 1) G2_KT(11, 1)
  *(short8*)((char*)&ldsw[0][0] + tid * 16) = c0;
  __syncthreads();

  // P6: kt12 (GEMM2) from buf0
  G2_KT(12, 0)

  // ---- || resp - sig ||^2 (sig f32 coalesced, b2 already in acc2) ----
  float ssq[2] = {0.f, 0.f};
#pragma unroll
  for (int nt = 0; nt < 8; ++nt) {
    f32x4 sv = *(const f32x4*)(sig + (size_t)un * DD + nt * 16 + lg * 4);
#pragma unroll
    for (int ut = 0; ut < 2; ++ut) {
#pragma unroll
      for (int r = 0; r < 4; ++r) {
        float d = acc2[nt][ut][r] - sv[r];
        ssq[ut] = fmaf(d, d, ssq[ut]);
      }
    }
  }
  ssq[0] += __shfl_xor(ssq[0], 16, 64); ssq[0] += __shfl_xor(ssq[0], 32, 64);
  ssq[1] += __shfl_xor(ssq[1], 16, 64); ssq[1] += __shfl_xor(ssq[1], 32, 64);

  // ---- accept / outputs: lanes 0..15, natural order (coalesced) ----
  if (lane < 16) {
    float px = pos[un * 3 + 0], py = pos[un * 3 + 1], pz = pos[un * 3 + 2];
    float ox = offs[un * 3 + 0], oy = offs[un * 3 + 1], oz = offs[un * 3 + 2];
    bool ok = ssq[1] <= ssq[0];
    out_stab[un] = sqrtf(ok ? ssq[1] : ssq[0]);
    out_pos[un * 3 + 0] = ok ? px + ox : px;
    out_pos[un * 3 + 1] = ok ? py + oy : py;
    out_pos[un * 3 + 2] = ok ? pz + oz : pz;
  }
#undef WRBUF
#undef SIG_KT
#undef ROW_KT
#undef G2_KT
}

extern "C" void kernel_launch(void* const* d_in, const int* in_sizes, int n_in,
                              void* d_out, int out_size, void* d_ws, size_t ws_size,
                              hipStream_t stream) {
  const float* field = (const float*)d_in[0];
  const float* pos   = (const float*)d_in[1];
  const float* sig   = (const float*)d_in[2];
  const float* offs  = (const float*)d_in[3];
  const float* W1    = (const float*)d_in[4];
  const float* b1    = (const float*)d_in[5];
  const float* W2    = (const float*)d_in[6];
  const float* b2    = (const float*)d_in[7];
  float* out_stab = (float*)d_out;
  float* out_pos  = out_stab + NU;

  char* ws = (char*)d_ws;
  unsigned short* fpad = (unsigned short*)ws;                 // 4,812,208 B (+slack)
  unsigned short* wall = (unsigned short*)(ws + 4812800);     // 106,496 B (13 x 8KB)

  prep_field<<<(PG * PG * PG + 255) / 256, 256, 0, stream>>>(field, fpad);
  prep_w<<<26, 256, 0, stream>>>(W1, W2, wall);
  atu_main<<<NU / 128, 512, 0, stream>>>(pos, sig, offs, b1, b2,
                                         fpad, wall, out_stab, out_pos);
}